// Round 14
// baseline (717.474 us; speedup 1.0000x reference)
//
#include <hip/hip_runtime.h>

#define BB 256
#define SS 1024
#define TT 128
#define EN 127          // END state (row EN of trans = -1e4)
#define IMIN -10000.0f
#define L2E 1.4426950408889634f
#define LN2f 0.6931471805599453f

typedef _Float16 half2v __attribute__((ext_vector_type(2)));

__device__ __forceinline__ float fdot2(unsigned a, unsigned b, float c) {
#if __has_builtin(__builtin_amdgcn_fdot2)
    return __builtin_amdgcn_fdot2(__builtin_bit_cast(half2v, a),
                                  __builtin_bit_cast(half2v, b), c, false);
#else
    float d;
    asm volatile("v_dot2_f32_f16 %0, %1, %2, %3"
                 : "=v"(d) : "v"(a), "v"(b), "v"(c));
    return d;
#endif
}
__device__ __forceinline__ unsigned pk16(float a, float b) {
    return __builtin_bit_cast(unsigned, __builtin_amdgcn_cvt_pkrtz(a, b));
}
template<int CTRL>
__device__ __forceinline__ float dpp_mov(float x) {
    return __int_as_float(__builtin_amdgcn_update_dpp(
        0, __float_as_int(x), CTRL, 0xF, 0xF, true));
}
// wave64 reduces: 4 DPP stages within 16 (r12-proven family) + 2 shfl
__device__ __forceinline__ float wmax64(float x) {
    x = fmaxf(x, dpp_mov<0xB1>(x));    // quad xor1
    x = fmaxf(x, dpp_mov<0x4E>(x));    // quad xor2
    x = fmaxf(x, dpp_mov<0x141>(x));   // row_half_mirror (8-group)
    x = fmaxf(x, dpp_mov<0x140>(x));   // row_mirror (16-group)
    x = fmaxf(x, __shfl_xor(x, 16));
    x = fmaxf(x, __shfl_xor(x, 32));
    return x;
}
__device__ __forceinline__ float wsum64(float x) {
    x += dpp_mov<0xB1>(x);
    x += dpp_mov<0x4E>(x);
    x += dpp_mov<0x141>(x);
    x += dpp_mov<0x140>(x);
    x += __shfl_xor(x, 16);
    x += __shfl_xor(x, 32);
    return x;
}

// ONE WAVE per batch (64 threads) -> NO barriers ever: a wave is one in-order
// stream; LDS write->read ordering is lgkmcnt-only. This removes the ~500cy
// fixed barrier+resume+round-trip cost that r8-r13 proved invariant (~870-950
// cy/step across all multi-wave structures).
// Lane l owns rows 2l,2l+1; P rows resident as f16 pairs (128 VGPRs);
// matvec = 128 v_dot2_f32_f16 (f32 accum). v (128 f16, 256B) broadcast via
// 16 ds_read_b128; per-step EXACT wave-max normalization keeps v in (0,1]
// (f16-safe; sub-2^-24 states flush to 0 with no error persistence since
// alpha'_i depends only on the shared LSE, not state i's own past).
__global__ __launch_bounds__(64, 1) void crf_fwd(const float* __restrict__ feats,
                                                 const int* __restrict__ blen,
                                                 const float* __restrict__ trans,
                                                 float* __restrict__ out)
{
    const int lane = threadIdx.x;
    const int b    = blockIdx.x;
    const int r0   = 2 * lane, r1 = 2 * lane + 1;

    __shared__ __align__(16) unsigned vbuf[64];   // f16x2 col pairs

    const float* fb = feats + (size_t)b * (SS * TT);
    const int L = blen[b];

    // ---- init: P rows -> f16 registers (normalized 2^(T2-rm)), row sums ----
    const float* t0 = trans + (size_t)r0 * TT;
    const float* t1 = trans + (size_t)r1 * TT;
    float rm0 = -3.4e38f, rm1 = -3.4e38f;
    #pragma unroll
    for (int k = 0; k < 32; ++k) {
        float4 a = ((const float4*)t0)[k];
        rm0 = fmaxf(rm0, fmaxf(fmaxf(a.x, a.y), fmaxf(a.z, a.w)));
        float4 c = ((const float4*)t1)[k];
        rm1 = fmaxf(rm1, fmaxf(fmaxf(c.x, c.y), fmaxf(c.z, c.w)));
    }
    rm0 *= L2E; rm1 *= L2E;     // max(T2) = L2E * max(T) (L2E > 0)

    unsigned P0[64], P1[64];
    float S0 = 0.f, S1 = 0.f;
    #pragma unroll
    for (int k = 0; k < 32; ++k) {
        float4 a = ((const float4*)t0)[k];
        float e0 = exp2f(fmaf(a.x, L2E, -rm0)), e1 = exp2f(fmaf(a.y, L2E, -rm0));
        float e2 = exp2f(fmaf(a.z, L2E, -rm0)), e3 = exp2f(fmaf(a.w, L2E, -rm0));
        S0 += (e0 + e1) + (e2 + e3);
        P0[2 * k] = pk16(e0, e1); P0[2 * k + 1] = pk16(e2, e3);
        float4 c = ((const float4*)t1)[k];
        float g0 = exp2f(fmaf(c.x, L2E, -rm1)), g1 = exp2f(fmaf(c.y, L2E, -rm1));
        float g2 = exp2f(fmaf(c.z, L2E, -rm1)), g3 = exp2f(fmaf(c.w, L2E, -rm1));
        S1 += (g0 + g1) + (g2 + g3);
        P1[2 * k] = pk16(g0, g1); P1[2 * k + 1] = pk16(g2, g3);
    }

    // exact step 0 (alpha0 = delta on START, col START = -1e4):
    // A1 = f0*L2E + IMIN*L2E + log2(1 + sum_j 2^T2_ij), anchored at
    // rmc = max(rm,0) so row EN (rm = -14427) degrades gracefully (r4 fix).
    float2 f0 = *(const float2*)(fb + r0);
    float rmc0 = fmaxf(rm0, 0.f), rmc1 = fmaxf(rm1, 0.f);
    float A10 = fmaf(f0.x, L2E, (IMIN * L2E) + rmc0 +
                     log2f(fmaf(S0, exp2f(rm0 - rmc0), exp2f(-rmc0))));
    float A11 = fmaf(f0.y, L2E, (IMIN * L2E) + rmc1 +
                     log2f(fmaf(S1, exp2f(rm1 - rmc1), exp2f(-rmc1))));

    float m0 = wmax64(fmaxf(A10, A11));
    float sh = m0;
    float vf0 = exp2f(A10 - m0), vf1 = exp2f(A11 - m0);   // <= 1
    vbuf[lane] = pk16(vf0, vf1);

    // ---- main loop: no barriers; feature prefetched one step ahead ----
    float2 fcur = *(const float2*)(fb + TT + r0);   // feats[1]
    for (int s = 1; s < L; ++s) {
        int sn = (s + 1 < SS) ? s + 1 : SS - 1;
        float2 fnx = *(const float2*)(fb + (size_t)sn * TT + r0);
        asm volatile("" :: "v"(fnx.x), "v"(fnx.y));   // pin prefetch issue here

        // broadcast-read the whole v (16 x ds_read_b128, same addr all lanes)
        uint4 VA[16];
        const uint4* vv = (const uint4*)vbuf;
        #pragma unroll
        for (int p = 0; p < 16; ++p) VA[p] = vv[p];

        // ef off the LDS critical path
        float ef0 = exp2f(fmaf(fcur.x, L2E, rm0));
        float ef1 = exp2f(fmaf(fcur.y, L2E, rm1));

        float a0 = 0.f, a1 = 0.f, a2 = 0.f, a3 = 0.f;
        float b0 = 0.f, b1 = 0.f, b2 = 0.f, b3 = 0.f;
        #pragma unroll
        for (int p = 0; p < 16; ++p) {
            a0 = fdot2(P0[4 * p + 0], VA[p].x, a0);
            a1 = fdot2(P0[4 * p + 1], VA[p].y, a1);
            a2 = fdot2(P0[4 * p + 2], VA[p].z, a2);
            a3 = fdot2(P0[4 * p + 3], VA[p].w, a3);
            b0 = fdot2(P1[4 * p + 0], VA[p].x, b0);
            b1 = fdot2(P1[4 * p + 1], VA[p].y, b1);
            b2 = fdot2(P1[4 * p + 2], VA[p].z, b2);
            b3 = fdot2(P1[4 * p + 3], VA[p].w, b3);
        }
        float u0 = (a0 + a1) + (a2 + a3);
        float u1 = (b0 + b1) + (b2 + b3);
        float y0 = ef0 * u0, y1 = ef1 * u1;     // y_i = 2^(A'_i - sh)

        float m = wmax64(fmaxf(y0, y1));        // exact max -> v' in (0,1]
        float rinv = __builtin_amdgcn_rcpf(m);
        vf0 = y0 * rinv; vf1 = y1 * rinv;
        sh += log2f(m);
        vbuf[lane] = pk16(vf0, vf1);            // in-order: next reads see it
        fcur = fnx;
    }

    // ---- epilogue: out = ln2 * log2 sum_j 2^(A_j + T2[EN][j]) ----
    float A0 = sh + log2f(vf0);                 // log2(0) = -inf benign
    float A1e = sh + log2f(vf1);
    float w0 = fmaf(trans[(size_t)EN * TT + r0], L2E, A0);
    float w1 = fmaf(trans[(size_t)EN * TT + r1], L2E, A1e);
    float mm = wmax64(fmaxf(w0, w1));
    float e  = exp2f(w0 - mm) + exp2f(w1 - mm);
    float ss = wsum64(e);
    if (lane == 0) out[b] = (mm + log2f(ss)) * LN2f;
}

extern "C" void kernel_launch(void* const* d_in, const int* in_sizes, int n_in,
                              void* d_out, int out_size, void* d_ws, size_t ws_size,
                              hipStream_t stream) {
    const float* feats = (const float*)d_in[0];
    const int*   blen  = (const int*)d_in[1];
    const float* trans = (const float*)d_in[2];
    float*       o     = (float*)d_out;
    crf_fwd<<<dim3(BB), dim3(64), 0, stream>>>(feats, blen, trans, o);
}